// Round 5
// baseline (2417.604 us; speedup 1.0000x reference)
//
#include <hip/hip_runtime.h>
#include <hip/hip_bf16.h>

typedef __bf16 bf16;
typedef __bf16 bf16x8 __attribute__((ext_vector_type(8)));
typedef float f32x4 __attribute__((ext_vector_type(4)));

#define BM 256
#define BN 256
#define BK 64
#define HDIM 512

// async global->LDS DMA: 16B per lane, LDS dest = wave-uniform base + lane*16
__device__ __forceinline__ void async_cp16(const bf16* g, bf16* l) {
    __builtin_amdgcn_global_load_lds(
        (const __attribute__((address_space(1))) void*)g,
        (__attribute__((address_space(3))) void*)l, 16, 0, 0);
}

// C = A @ Bt^T (+ epilogue). A bf16 [rows][512] via A1 (k<512) / A2 (k>=512).
// Bt bf16 [512][K] pre-transposed. Accumulate f32, state stored bf16.
// MODE 0: D = acc + bias + X1                         (e update)
// MODE 1: D = acc + bias                              (fm / wm)
// MODE 2: g = sigmoid(acc+bias); D = X1*(1-g) + X2*g  (gated f / w update)
// MODE 3: D = gelu_exact(acc + bias)                  (head hidden)
// XT: dtype of X1 (f32 at layer 0, bf16 after). X2 always bf16.
//
// r5 = r4 RESUBMITTED UNCHANGED. r4's "container failed twice" is judged infra
// (3/5 rounds failed at container level incl. the verified-structure r4; the
// successful r2 run showed a 1294 s push). Kernel audit found no fault:
// wave-uniform LDS dests, bijective T1 at all nc, consistent T2 involution,
// VGPR ~210 < 256 cap, uniform barriers.
//  - 256x256 tile, 8 waves: MFMA per staged byte 2x vs r2 (620 vs 1170 cyc
//    per 64 KB K-step), grid 256 blocks = 1/CU (single residency round)
//  - T1 XCD swizzle (2 n-sharers), T2 XOR involution: counter-verified in r2
//    (FETCH 107->58 MB, bank conflicts 6.3e6->0)
template<int MODE, int KT, typename XT>
__global__ void __launch_bounds__(512, 2)
gemm_k(const bf16* __restrict__ A1, const bf16* __restrict__ A2,
       const bf16* __restrict__ Bt, const float* __restrict__ bias,
       const XT* __restrict__ X1, const bf16* __restrict__ X2,
       bf16* __restrict__ D)
{
    __shared__ __align__(16) bf16 As[2][BM * BK];   // 32 KB per buf
    __shared__ __align__(16) bf16 Bs[2][BN * BK];   // 32 KB per buf -> 128 KB total
    const int K = KT * BK;
    const int tid  = threadIdx.x;
    const int lane = tid & 63;
    const int wv   = tid >> 6;                       // 0..7

    // ---- T1: XCD-chunked bijective swizzle (m204 formula) ----
    const int nwg = gridDim.x * gridDim.y;                // x-dim is 2
    const int hw  = blockIdx.y * gridDim.x + blockIdx.x;  // hw id -> XCD = hw&7
    const int xcd = hw & 7, within = hw >> 3;
    const int q = nwg >> 3, rr = nwg & 7;
    const int logical = (xcd < rr ? xcd * (q + 1) : rr * (q + 1) + (xcd - rr) * q)
                        + within;
    const int m_blk = (logical >> 1) * BM;           // consecutive logicals share
    const int n_blk = (logical & 1) * BN;            // the same A-panel + XCD

    f32x4 acc[8][4] = {};                            // wave owns 128x64 of C

    const int srow = lane >> 3;                      // 0..7: row within 8-row stripe
    // T2: lane fetches the global chunk that belongs at its LINEAR lds slot
    // under the involution chunk ^= (row&7)
    const int schunk = ((lane & 7) ^ srow) * 8;      // 0..56, element offset
    const int wm = (wv >> 2) * 128;                  // 2 waves in M
    const int wn = (wv & 3) * 64;                    // 4 waves in N

    auto stage = [&](int kt, int buf) {
        const int k0 = kt * BK;
        const bf16* Ab; int kc;
        if (k0 < 512) { Ab = A1; kc = k0; } else { Ab = A2; kc = k0 - 512; }
#pragma unroll
        for (int s = 0; s < 4; ++s) {
            const int r = wv * 32 + s * 8;   // wave stages rows [wv*32, wv*32+32)
            async_cp16(Ab + (size_t)(m_blk + r + srow) * HDIM + kc + schunk,
                       &As[buf][r * BK]);
            async_cp16(Bt + (size_t)(n_blk + r + srow) * K + k0 + schunk,
                       &Bs[buf][r * BK]);
        }
    };

    stage(0, 0);
    for (int kt = 0; kt < KT; ++kt) {
        const int cur = kt & 1;
        __syncthreads();                       // drains vmcnt: tile kt landed
        if (kt + 1 < KT) stage(kt + 1, cur ^ 1);  // prefetch flies during MFMA
#pragma unroll
        for (int kk = 0; kk < BK; kk += 32) {
            bf16x8 af[8], bfr[4];
            const int cl = (kk >> 3) + (lane >> 4);   // logical 16B chunk 0..7
            const int r7 = lane & 7;                  // == row&7 for our rows
#pragma unroll
            for (int t = 0; t < 8; ++t) {
                const int ra = wm + t * 16 + (lane & 15);
                af[t]  = *(const bf16x8*)&As[cur][ra * BK + ((cl ^ r7) << 3)];
            }
#pragma unroll
            for (int t = 0; t < 4; ++t) {
                const int rb = wn + t * 16 + (lane & 15);
                bfr[t] = *(const bf16x8*)&Bs[cur][rb * BK + ((cl ^ r7) << 3)];
            }
#pragma unroll
            for (int tm = 0; tm < 8; ++tm)
#pragma unroll
                for (int tn = 0; tn < 4; ++tn)
                    acc[tm][tn] = __builtin_amdgcn_mfma_f32_16x16x32_bf16(
                        af[tm], bfr[tn], acc[tm][tn], 0, 0, 0);
        }
    }

    // epilogue: C/D layout col = lane&15, row = (lane>>4)*4 + r  (m89-verified)
#pragma unroll
    for (int tn = 0; tn < 4; ++tn) {
        const int n = n_blk + wn + tn * 16 + (lane & 15);
        const float bn = bias[n];
#pragma unroll
        for (int tm = 0; tm < 8; ++tm) {
            const int mb = m_blk + wm + tm * 16 + (lane >> 4) * 4;
#pragma unroll
            for (int r = 0; r < 4; ++r) {
                const size_t idx = (size_t)(mb + r) * HDIM + n;
                float v = acc[tm][tn][r] + bn;
                if (MODE == 0) {
                    v += (float)X1[idx];
                } else if (MODE == 2) {
                    const float g = 1.0f / (1.0f + __expf(-v));
                    v = (float)X1[idx] * (1.0f - g) + (float)X2[idx] * g;
                } else if (MODE == 3) {
                    v = 0.5f * v * (1.0f + erff(v * 0.70710678118654752f));
                }
                D[idx] = (bf16)v;
            }
        }
    }
}

// f32 [R][C] -> bf16 [C][R] transpose+convert, batched over blockIdx.z
__global__ void __launch_bounds__(256)
transpose_cvt_k(const float* __restrict__ src, bf16* __restrict__ dst, int R, int C)
{
    __shared__ bf16 t[64][65];
    const size_t mat = (size_t)blockIdx.z * R * C;
    const int r0 = blockIdx.y * 64, c0 = blockIdx.x * 64;
    for (int i = threadIdx.x; i < 4096; i += 256) {
        const int r = i >> 6, c = i & 63;
        t[c][r] = (bf16)src[mat + (size_t)(r0 + r) * C + (c0 + c)];
    }
    __syncthreads();
    for (int i = threadIdx.x; i < 4096; i += 256) {
        const int r = i >> 6, c = i & 63;
        dst[mat + (size_t)(c0 + r) * R + (r0 + c)] = t[r][c];
    }
}

// f32 -> bf16 elementwise convert, 8 elems/thread
__global__ void __launch_bounds__(256)
cvt_k(const float* __restrict__ src, bf16* __restrict__ dst)
{
    const size_t i = ((size_t)blockIdx.x * 256 + threadIdx.x) * 8;
    f32x4 a = *(const f32x4*)(src + i);
    f32x4 b = *(const f32x4*)(src + i + 4);
    bf16x8 v;
#pragma unroll
    for (int j = 0; j < 4; ++j) { v[j] = (bf16)a[j]; v[4 + j] = (bf16)b[j]; }
    *(bf16x8*)(dst + i) = v;
}

// out[:, off:off+OH] = G @ W2 + b2 ; one wave per row; G bf16, W2/b2/out f32
template<int OH>
__global__ void __launch_bounds__(256)
head2_k(const bf16* __restrict__ G, const float* __restrict__ W2,
        const float* __restrict__ b2, float* __restrict__ out, int off)
{
    const int lane = threadIdx.x & 63;
    const int row  = blockIdx.x * 4 + (threadIdx.x >> 6);
    const bf16x8 gv = *(const bf16x8*)&G[(size_t)row * HDIM + lane * 8];
    float p[OH];
#pragma unroll
    for (int jj = 0; jj < OH; ++jj) p[jj] = 0.f;
#pragma unroll
    for (int j = 0; j < 8; ++j) {
        const float g = (float)gv[j];
        const int k = lane * 8 + j;
#pragma unroll
        for (int jj = 0; jj < OH; ++jj)
            p[jj] += g * W2[k * OH + jj];
    }
#pragma unroll
    for (int jj = 0; jj < OH; ++jj)
        for (int o = 32; o > 0; o >>= 1)
            p[jj] += __shfl_xor(p[jj], o, 64);
    if (lane == 0) {
#pragma unroll
        for (int jj = 0; jj < OH; ++jj)
            out[(size_t)row * 7 + off + jj] = p[jj] + b2[jj];
    }
}

extern "C" void kernel_launch(void* const* d_in, const int* in_sizes, int n_in,
                              void* d_out, int out_size, void* d_ws, size_t ws_size,
                              hipStream_t stream)
{
    (void)in_sizes; (void)n_in; (void)out_size;
    const float* sh   = (const float*)d_in[0];
    const float* e0   = (const float*)d_in[1];
    const float* f0   = (const float*)d_in[2];
    const float* w0   = (const float*)d_in[3];
    const float* s2eb = (const float*)d_in[5];
    const float* tfb  = (const float*)d_in[7];
    const float* fwb  = (const float*)d_in[9];
    const float* fgb  = (const float*)d_in[11];
    const float* wgb  = (const float*)d_in[13];
    float* out = (float*)d_out;

    // ---- workspace layout (all bf16) ----
    char* p = (char*)d_ws;
    auto balloc = [&](size_t elems) { bf16* q = (bf16*)p; p += elems * sizeof(bf16); return q; };
    bf16* s2eWt = balloc((size_t)5 * 512 * 512);
    bf16* tfWt  = balloc((size_t)5 * 512 * 1024);
    bf16* fwWt  = balloc((size_t)5 * 512 * 1024);
    bf16* fgWt  = balloc((size_t)5 * 512 * 512);
    bf16* wgWt  = balloc((size_t)5 * 512 * 512);
    bf16* W1t[4];
    for (int h = 0; h < 4; ++h) W1t[h] = balloc((size_t)512 * 512);

    // row-chunking hedge: 5 bf16 chunk buffers must fit remaining ws
    const size_t wbytes = (size_t)(p - (char*)d_ws);
    int nc = 1;
    while (nc < 32 &&
           wbytes + 5ull * (32768 / nc) * HDIM * sizeof(bf16) > ws_size)
        nc *= 2;
    const int rows = 32768 / nc;
    const size_t CH = (size_t)rows * HDIM;
    bf16* shb  = balloc(CH);
    bf16* ebuf = balloc(CH);
    bf16* fbuf = balloc(CH);
    bf16* wbuf = balloc(CH);
    bf16* mbuf = balloc(CH);

    const dim3 blk(256);
    const dim3 gblk(512);
    // weight prep: f32 W[K][N] -> bf16 Wt[N][K] (K-contiguous)
    transpose_cvt_k<<<dim3(8,  8, 5), blk, 0, stream>>>((const float*)d_in[4],  s2eWt, 512, 512);
    transpose_cvt_k<<<dim3(8, 16, 5), blk, 0, stream>>>((const float*)d_in[6],  tfWt, 1024, 512);
    transpose_cvt_k<<<dim3(8, 16, 5), blk, 0, stream>>>((const float*)d_in[8],  fwWt, 1024, 512);
    transpose_cvt_k<<<dim3(8,  8, 5), blk, 0, stream>>>((const float*)d_in[10], fgWt, 512, 512);
    transpose_cvt_k<<<dim3(8,  8, 5), blk, 0, stream>>>((const float*)d_in[12], wgWt, 512, 512);
    for (int h = 0; h < 4; ++h)
        transpose_cvt_k<<<dim3(8, 8, 1), blk, 0, stream>>>((const float*)d_in[14 + h * 4], W1t[h], 512, 512);

    const dim3 gg(2, rows / 256);
    for (int c = 0; c < nc; ++c) {
        const size_t ro = (size_t)c * rows;
        cvt_k<<<(int)(CH / 2048), blk, 0, stream>>>(sh + ro * HDIM, shb);
        // ---- layer 0 (X1 reads are f32 originals) ----
        gemm_k<0, 8, float><<<gg, gblk, 0, stream>>>(shb, nullptr, s2eWt, s2eb,
                                                     e0 + ro * HDIM, nullptr, ebuf);
        gemm_k<1, 16, bf16><<<gg, gblk, 0, stream>>>(shb, ebuf, tfWt, tfb,
                                                     nullptr, nullptr, mbuf);
        gemm_k<2, 8, float><<<gg, gblk, 0, stream>>>(mbuf, nullptr, fgWt, fgb,
                                                     f0 + ro * HDIM, mbuf, fbuf);
        gemm_k<1, 16, bf16><<<gg, gblk, 0, stream>>>(ebuf, fbuf, fwWt, fwb,
                                                     nullptr, nullptr, mbuf);
        gemm_k<2, 8, float><<<gg, gblk, 0, stream>>>(mbuf, nullptr, wgWt, wgb,
                                                     w0 + ro * HDIM, mbuf, wbuf);
        // ---- layers 1..4 (all-bf16 state) ----
        for (int i = 1; i < 5; ++i) {
            gemm_k<0, 8, bf16><<<gg, gblk, 0, stream>>>(shb, nullptr, s2eWt + (size_t)i * 512 * 512,
                                                        s2eb + i * 512, ebuf, nullptr, ebuf);
            gemm_k<1, 16, bf16><<<gg, gblk, 0, stream>>>(shb, ebuf, tfWt + (size_t)i * 512 * 1024,
                                                         tfb + i * 512, nullptr, nullptr, mbuf);
            gemm_k<2, 8, bf16><<<gg, gblk, 0, stream>>>(mbuf, nullptr, fgWt + (size_t)i * 512 * 512,
                                                        fgb + i * 512, fbuf, mbuf, fbuf);
            gemm_k<1, 16, bf16><<<gg, gblk, 0, stream>>>(ebuf, fbuf, fwWt + (size_t)i * 512 * 1024,
                                                         fwb + i * 512, nullptr, nullptr, mbuf);
            gemm_k<2, 8, bf16><<<gg, gblk, 0, stream>>>(mbuf, nullptr, wgWt + (size_t)i * 512 * 512,
                                                        wgb + i * 512, wbuf, mbuf, wbuf);
        }
        // ---- heads ----
        const bf16* hx[4] = { shb, ebuf, fbuf, wbuf };
        float* outc = out + ro * 7;
        for (int h = 0; h < 4; ++h) {
            gemm_k<3, 8, bf16><<<gg, gblk, 0, stream>>>(hx[h], nullptr, W1t[h],
                                                        (const float*)d_in[15 + h * 4],
                                                        nullptr, nullptr, mbuf);
            const float* W2 = (const float*)d_in[16 + h * 4];
            const float* b2 = (const float*)d_in[17 + h * 4];
            if (h == 0)      head2_k<3><<<rows / 4, blk, 0, stream>>>(mbuf, W2, b2, outc, 0);
            else if (h == 1) head2_k<1><<<rows / 4, blk, 0, stream>>>(mbuf, W2, b2, outc, 3);
            else if (h == 2) head2_k<1><<<rows / 4, blk, 0, stream>>>(mbuf, W2, b2, outc, 4);
            else             head2_k<2><<<rows / 4, blk, 0, stream>>>(mbuf, W2, b2, outc, 5);
        }
    }
}

// Round 6
// 1531.906 us; speedup vs baseline: 1.5782x; 1.5782x over previous
//
#include <hip/hip_runtime.h>
#include <hip/hip_bf16.h>

typedef __bf16 bf16;
typedef __bf16 bf16x8 __attribute__((ext_vector_type(8)));
typedef float f32x4 __attribute__((ext_vector_type(4)));

#define BM 128
#define BN 128
#define BK 64
#define HDIM 512

// async global->LDS DMA: 16B per lane, LDS dest = wave-uniform base + lane*16
__device__ __forceinline__ void async_cp16(const bf16* g, bf16* l) {
    __builtin_amdgcn_global_load_lds(
        (const __attribute__((address_space(1))) void*)g,
        (__attribute__((address_space(3))) void*)l, 16, 0, 0);
}

// C = A @ Bt^T (+ epilogue). A bf16 [rows][512] via A1 (k<512) / A2 (k>=512).
// Bt bf16 [512][K] pre-transposed. Accumulate f32, state stored bf16.
// MODE 0: D = acc + bias + X1                         (e update)
// MODE 1: D = acc + bias                              (fm / wm)
// MODE 2: g = sigmoid(acc+bias); D = X1*(1-g) + X2*g  (gated f / w update)
// MODE 3: D = gelu_exact(acc + bias)                  (head hidden)
// XT: dtype of X1 (f32 at layer 0, bf16 after). X2 always bf16.
//
// r6 = the audited r3 kernel, resubmitted: r2's verified 128^2 base
// (T1 XCD swizzle + T2 XOR involution, counter-verified: FETCH 107->58 MB,
// bank conflicts 6.3e6->0) + T4 counted-vmcnt depth-2 pipeline.
// Rationale: r4's clean __syncthreads kernel failed the container twice and
// the IDENTICAL r5 passed -> container failures are infra noise; r1/r3 never
// falsified this design. r5 also showed 256^2/1-block-per-CU loses L2 locality
// (FETCH 160 MB) -> stay at 128^2 with 2 blocks/CU.
// Loop: issue stage(kt+1) FIRST, then s_waitcnt vmcnt(8) (= tile kt landed,
// kt+1 still in flight), s_barrier, MFMA on kt, lgkmcnt(0), s_barrier.
// Never drains vmcnt to 0 mid-loop. sched_barrier(0) pins ds_reads inside
// the window (global_load_lds has no register def -> no dep edge; rule #18).
template<int MODE, int KT, typename XT>
__global__ void __launch_bounds__(256)
gemm_k(const bf16* __restrict__ A1, const bf16* __restrict__ A2,
       const bf16* __restrict__ Bt, const float* __restrict__ bias,
       const XT* __restrict__ X1, const bf16* __restrict__ X2,
       bf16* __restrict__ D)
{
    __shared__ __align__(16) bf16 As[2][BM * BK];
    __shared__ __align__(16) bf16 Bs[2][BN * BK];
    const int K = KT * BK;
    const int tid  = threadIdx.x;
    const int lane = tid & 63;
    const int wv   = tid >> 6;

    // ---- T1: XCD-chunked bijective swizzle (m204 formula) ----
    const int nwg = gridDim.x * gridDim.y;                // x-dim is 4
    const int hw  = blockIdx.y * gridDim.x + blockIdx.x;  // hw id -> XCD = hw&7
    const int xcd = hw & 7, within = hw >> 3;
    const int q = nwg >> 3, rr = nwg & 7;
    const int logical = (xcd < rr ? xcd * (q + 1) : rr * (q + 1) + (xcd - rr) * q)
                        + within;
    const int m_blk = (logical >> 2) * BM;           // consecutive logicals share
    const int n_blk = (logical & 3) * BN;            // the same A-panel + XCD

    f32x4 acc[4][4] = {};

    const int srow = lane >> 3;                      // 0..7: row within 8-row stripe
    // T2: lane fetches the global chunk that belongs at its LINEAR lds slot
    // under the involution chunk ^= (row&7)
    const int schunk = ((lane & 7) ^ srow) * 8;      // 0..56, element offset
    const int wm = (wv >> 1) * 64;
    const int wn = (wv & 1) * 64;

    auto stage = [&](int kt, int buf) {
        const int k0 = kt * BK;
        const bf16* Ab; int kc;
        if (k0 < 512) { Ab = A1; kc = k0; } else { Ab = A2; kc = k0 - 512; }
#pragma unroll
        for (int s = 0; s < 4; ++s) {
            const int r = wv * 32 + s * 8;   // wave stages rows [wv*32, wv*32+32)
            async_cp16(Ab + (size_t)(m_blk + r + srow) * HDIM + kc + schunk,
                       &As[buf][r * BK]);
            async_cp16(Bt + (size_t)(n_blk + r + srow) * K + k0 + schunk,
                       &Bs[buf][r * BK]);
        }
    };
    // each stage() = exactly 8 global_load_lds per wave -> vmcnt(8) ==
    // "previous tile fully landed, current prefetch still in flight"

    stage(0, 0);
    for (int kt = 0; kt < KT; ++kt) {
        const int cur = kt & 1;
        // issue next tile BEFORE waiting; buf cur^1 is safe to overwrite
        // (all reads of it finished before the end-of-iter barrier of kt-1)
        if (kt + 1 < KT) {
            stage(kt + 1, cur ^ 1);
            asm volatile("s_waitcnt vmcnt(8)" ::: "memory");   // tile kt landed
        } else {
            asm volatile("s_waitcnt vmcnt(0)" ::: "memory");
        }
        __builtin_amdgcn_sched_barrier(0);
        __builtin_amdgcn_s_barrier();          // all waves: tile kt landed
        __builtin_amdgcn_sched_barrier(0);
#pragma unroll
        for (int kk = 0; kk < BK; kk += 32) {
            bf16x8 af[4], bfr[4];
            const int cl = (kk >> 3) + (lane >> 4);   // logical 16B chunk 0..7
            const int r7 = lane & 7;                  // == row&7 for our rows
#pragma unroll
            for (int t = 0; t < 4; ++t) {
                const int ra = wm + t * 16 + (lane & 15);
                const int rb = wn + t * 16 + (lane & 15);
                af[t]  = *(const bf16x8*)&As[cur][ra * BK + ((cl ^ r7) << 3)];
                bfr[t] = *(const bf16x8*)&Bs[cur][rb * BK + ((cl ^ r7) << 3)];
            }
#pragma unroll
            for (int tm = 0; tm < 4; ++tm)
#pragma unroll
                for (int tn = 0; tn < 4; ++tn)
                    acc[tm][tn] = __builtin_amdgcn_mfma_f32_16x16x32_bf16(
                        af[tm], bfr[tn], acc[tm][tn], 0, 0, 0);
        }
        __builtin_amdgcn_sched_barrier(0);
        asm volatile("s_waitcnt lgkmcnt(0)" ::: "memory");  // my reads of cur done
        __builtin_amdgcn_s_barrier();          // everyone's reads of cur done
        __builtin_amdgcn_sched_barrier(0);
    }

    // epilogue: C/D layout col = lane&15, row = (lane>>4)*4 + r  (m89-verified)
#pragma unroll
    for (int tn = 0; tn < 4; ++tn) {
        const int n = n_blk + wn + tn * 16 + (lane & 15);
        const float bn = bias[n];
#pragma unroll
        for (int tm = 0; tm < 4; ++tm) {
            const int mb = m_blk + wm + tm * 16 + (lane >> 4) * 4;
#pragma unroll
            for (int r = 0; r < 4; ++r) {
                const size_t idx = (size_t)(mb + r) * HDIM + n;
                float v = acc[tm][tn][r] + bn;
                if (MODE == 0) {
                    v += (float)X1[idx];
                } else if (MODE == 2) {
                    const float g = 1.0f / (1.0f + __expf(-v));
                    v = (float)X1[idx] * (1.0f - g) + (float)X2[idx] * g;
                } else if (MODE == 3) {
                    v = 0.5f * v * (1.0f + erff(v * 0.70710678118654752f));
                }
                D[idx] = (bf16)v;
            }
        }
    }
}

// f32 [R][C] -> bf16 [C][R] transpose+convert, batched over blockIdx.z
__global__ void __launch_bounds__(256)
transpose_cvt_k(const float* __restrict__ src, bf16* __restrict__ dst, int R, int C)
{
    __shared__ bf16 t[64][65];
    const size_t mat = (size_t)blockIdx.z * R * C;
    const int r0 = blockIdx.y * 64, c0 = blockIdx.x * 64;
    for (int i = threadIdx.x; i < 4096; i += 256) {
        const int r = i >> 6, c = i & 63;
        t[c][r] = (bf16)src[mat + (size_t)(r0 + r) * C + (c0 + c)];
    }
    __syncthreads();
    for (int i = threadIdx.x; i < 4096; i += 256) {
        const int r = i >> 6, c = i & 63;
        dst[mat + (size_t)(c0 + r) * R + (r0 + c)] = t[r][c];
    }
}

// f32 -> bf16 elementwise convert, 8 elems/thread
__global__ void __launch_bounds__(256)
cvt_k(const float* __restrict__ src, bf16* __restrict__ dst)
{
    const size_t i = ((size_t)blockIdx.x * 256 + threadIdx.x) * 8;
    f32x4 a = *(const f32x4*)(src + i);
    f32x4 b = *(const f32x4*)(src + i + 4);
    bf16x8 v;
#pragma unroll
    for (int j = 0; j < 4; ++j) { v[j] = (bf16)a[j]; v[4 + j] = (bf16)b[j]; }
    *(bf16x8*)(dst + i) = v;
}

// out[:, off:off+OH] = G @ W2 + b2 ; one wave per row; G bf16, W2/b2/out f32
template<int OH>
__global__ void __launch_bounds__(256)
head2_k(const bf16* __restrict__ G, const float* __restrict__ W2,
        const float* __restrict__ b2, float* __restrict__ out, int off)
{
    const int lane = threadIdx.x & 63;
    const int row  = blockIdx.x * 4 + (threadIdx.x >> 6);
    const bf16x8 gv = *(const bf16x8*)&G[(size_t)row * HDIM + lane * 8];
    float p[OH];
#pragma unroll
    for (int jj = 0; jj < OH; ++jj) p[jj] = 0.f;
#pragma unroll
    for (int j = 0; j < 8; ++j) {
        const float g = (float)gv[j];
        const int k = lane * 8 + j;
#pragma unroll
        for (int jj = 0; jj < OH; ++jj)
            p[jj] += g * W2[k * OH + jj];
    }
#pragma unroll
    for (int jj = 0; jj < OH; ++jj)
        for (int o = 32; o > 0; o >>= 1)
            p[jj] += __shfl_xor(p[jj], o, 64);
    if (lane == 0) {
#pragma unroll
        for (int jj = 0; jj < OH; ++jj)
            out[(size_t)row * 7 + off + jj] = p[jj] + b2[jj];
    }
}

extern "C" void kernel_launch(void* const* d_in, const int* in_sizes, int n_in,
                              void* d_out, int out_size, void* d_ws, size_t ws_size,
                              hipStream_t stream)
{
    (void)in_sizes; (void)n_in; (void)out_size;
    const float* sh   = (const float*)d_in[0];
    const float* e0   = (const float*)d_in[1];
    const float* f0   = (const float*)d_in[2];
    const float* w0   = (const float*)d_in[3];
    const float* s2eb = (const float*)d_in[5];
    const float* tfb  = (const float*)d_in[7];
    const float* fwb  = (const float*)d_in[9];
    const float* fgb  = (const float*)d_in[11];
    const float* wgb  = (const float*)d_in[13];
    float* out = (float*)d_out;

    // ---- workspace layout (all bf16) ----
    char* p = (char*)d_ws;
    auto balloc = [&](size_t elems) { bf16* q = (bf16*)p; p += elems * sizeof(bf16); return q; };
    bf16* s2eWt = balloc((size_t)5 * 512 * 512);
    bf16* tfWt  = balloc((size_t)5 * 512 * 1024);
    bf16* fwWt  = balloc((size_t)5 * 512 * 1024);
    bf16* fgWt  = balloc((size_t)5 * 512 * 512);
    bf16* wgWt  = balloc((size_t)5 * 512 * 512);
    bf16* W1t[4];
    for (int h = 0; h < 4; ++h) W1t[h] = balloc((size_t)512 * 512);

    // row-chunking hedge: 5 bf16 chunk buffers must fit remaining ws
    const size_t wbytes = (size_t)(p - (char*)d_ws);
    int nc = 1;
    while (nc < 32 &&
           wbytes + 5ull * (32768 / nc) * HDIM * sizeof(bf16) > ws_size)
        nc *= 2;
    const int rows = 32768 / nc;
    const size_t CH = (size_t)rows * HDIM;
    bf16* shb  = balloc(CH);
    bf16* ebuf = balloc(CH);
    bf16* fbuf = balloc(CH);
    bf16* wbuf = balloc(CH);
    bf16* mbuf = balloc(CH);

    const dim3 blk(256);
    // weight prep: f32 W[K][N] -> bf16 Wt[N][K] (K-contiguous)
    transpose_cvt_k<<<dim3(8,  8, 5), blk, 0, stream>>>((const float*)d_in[4],  s2eWt, 512, 512);
    transpose_cvt_k<<<dim3(8, 16, 5), blk, 0, stream>>>((const float*)d_in[6],  tfWt, 1024, 512);
    transpose_cvt_k<<<dim3(8, 16, 5), blk, 0, stream>>>((const float*)d_in[8],  fwWt, 1024, 512);
    transpose_cvt_k<<<dim3(8,  8, 5), blk, 0, stream>>>((const float*)d_in[10], fgWt, 512, 512);
    transpose_cvt_k<<<dim3(8,  8, 5), blk, 0, stream>>>((const float*)d_in[12], wgWt, 512, 512);
    for (int h = 0; h < 4; ++h)
        transpose_cvt_k<<<dim3(8, 8, 1), blk, 0, stream>>>((const float*)d_in[14 + h * 4], W1t[h], 512, 512);

    const dim3 gg(4, rows / 128);
    for (int c = 0; c < nc; ++c) {
        const size_t ro = (size_t)c * rows;
        cvt_k<<<(int)(CH / 2048), blk, 0, stream>>>(sh + ro * HDIM, shb);
        // ---- layer 0 (X1 reads are f32 originals) ----
        gemm_k<0, 8, float><<<gg, blk, 0, stream>>>(shb, nullptr, s2eWt, s2eb,
                                                    e0 + ro * HDIM, nullptr, ebuf);
        gemm_k<1, 16, bf16><<<gg, blk, 0, stream>>>(shb, ebuf, tfWt, tfb,
                                                    nullptr, nullptr, mbuf);
        gemm_k<2, 8, float><<<gg, blk, 0, stream>>>(mbuf, nullptr, fgWt, fgb,
                                                    f0 + ro * HDIM, mbuf, fbuf);
        gemm_k<1, 16, bf16><<<gg, blk, 0, stream>>>(ebuf, fbuf, fwWt, fwb,
                                                    nullptr, nullptr, mbuf);
        gemm_k<2, 8, float><<<gg, blk, 0, stream>>>(mbuf, nullptr, wgWt, wgb,
                                                    w0 + ro * HDIM, mbuf, wbuf);
        // ---- layers 1..4 (all-bf16 state) ----
        for (int i = 1; i < 5; ++i) {
            gemm_k<0, 8, bf16><<<gg, blk, 0, stream>>>(shb, nullptr, s2eWt + (size_t)i * 512 * 512,
                                                       s2eb + i * 512, ebuf, nullptr, ebuf);
            gemm_k<1, 16, bf16><<<gg, blk, 0, stream>>>(shb, ebuf, tfWt + (size_t)i * 512 * 1024,
                                                        tfb + i * 512, nullptr, nullptr, mbuf);
            gemm_k<2, 8, bf16><<<gg, blk, 0, stream>>>(mbuf, nullptr, fgWt + (size_t)i * 512 * 512,
                                                       fgb + i * 512, fbuf, mbuf, fbuf);
            gemm_k<1, 16, bf16><<<gg, blk, 0, stream>>>(ebuf, fbuf, fwWt + (size_t)i * 512 * 1024,
                                                        fwb + i * 512, nullptr, nullptr, mbuf);
            gemm_k<2, 8, bf16><<<gg, blk, 0, stream>>>(mbuf, nullptr, wgWt + (size_t)i * 512 * 512,
                                                       wgb + i * 512, wbuf, mbuf, wbuf);
        }
        // ---- heads ----
        const bf16* hx[4] = { shb, ebuf, fbuf, wbuf };
        float* outc = out + ro * 7;
        for (int h = 0; h < 4; ++h) {
            gemm_k<3, 8, bf16><<<gg, blk, 0, stream>>>(hx[h], nullptr, W1t[h],
                                                       (const float*)d_in[15 + h * 4],
                                                       nullptr, nullptr, mbuf);
            const float* W2 = (const float*)d_in[16 + h * 4];
            const float* b2 = (const float*)d_in[17 + h * 4];
            if (h == 0)      head2_k<3><<<rows / 4, blk, 0, stream>>>(mbuf, W2, b2, outc, 0);
            else if (h == 1) head2_k<1><<<rows / 4, blk, 0, stream>>>(mbuf, W2, b2, outc, 3);
            else if (h == 2) head2_k<1><<<rows / 4, blk, 0, stream>>>(mbuf, W2, b2, outc, 4);
            else             head2_k<2><<<rows / 4, blk, 0, stream>>>(mbuf, W2, b2, outc, 5);
        }
    }
}